// Round 2
// baseline (135.565 us; speedup 1.0000x reference)
//
#include <hip/hip_runtime.h>

// x:  [N=4, C=256, H=56, W=56] fp32
// w1: [N, 1, 32, 9,  H, W]     (3x3, pad 1)
// w2: [N, 1, 32, 25, H, W]     (5x5, pad 2)
// out:[N, 2, 1, C, H, W]
// out[n,b,c,h,w] = sum_p wB[n, c%32, p, h, w] * x[n, c, h+dh, w+dw] (zero pad)
//
// Structure: thread = (n, v, 2 consecutive w). Tap-major: accumulators for all
// 8 channel groups live in registers; weights are loaded once per row (float2)
// and reused 8x; x rows loaded as 3 aligned dwordx2 chunks, reused across taps.

#define N_  4
#define C_  256
#define H_  56
#define W_  56
#define HW_ 3136
#define WC_ 32
#define G_  8
#define W2_ 28        // float2 columns per row
#define HW2_ 1568     // float2 positions per plane

__global__ __launch_bounds__(256) void lconv_kernel(
    const float* __restrict__ x,
    const float* __restrict__ w1,
    const float* __restrict__ w2,
    float* __restrict__ out)
{
    const int gid = blockIdx.x * 256 + threadIdx.x;   // over N*WC*HW2 = 200704
    const int hw2 = gid % HW2_;
    const int nv  = gid / HW2_;                        // n*32 + v (heads=1)
    const int v   = nv % WC_;
    const int n   = nv / WC_;
    const int h   = hw2 / W2_;
    const int wb  = (hw2 % W2_) * 2;                   // 0..54, even
    const int hw  = h * W_ + wb;

    const float* w1t = w1 + (size_t)nv * 9  * HW_ + hw;
    const float* w2t = w2 + (size_t)nv * 25 * HW_ + hw;
    const float* xb  = x + ((size_t)n * C_ + v) * HW_ + hw;  // group-0 channel, this pixel

    float acc1x[G_], acc1y[G_], acc2x[G_], acc2y[G_];
    #pragma unroll
    for (int g = 0; g < G_; ++g) { acc1x[g]=0.f; acc1y[g]=0.f; acc2x[g]=0.f; acc2y[g]=0.f; }

    const bool aok = (wb > 0);        // left chunk fully valid unless wb==0
    const bool cok = (wb < W_ - 2);   // right chunk fully valid unless wb==54

    #pragma unroll
    for (int di = 0; di < 5; ++di) {
        const int hh = h + di - 2;
        const bool hok = (hh >= 0) && (hh < H_);

        // Per-pixel weight rows: loaded once, reused by all 8 groups.
        float2 wr2[5];
        #pragma unroll
        for (int dj = 0; dj < 5; ++dj)
            wr2[dj] = *(const float2*)(w2t + (size_t)(di * 5 + dj) * HW_);
        float2 wr1[3];
        if (di >= 1 && di <= 3) {
            #pragma unroll
            for (int dj = 0; dj < 3; ++dj)
                wr1[dj] = *(const float2*)(w1t + (size_t)((di - 1) * 3 + dj) * HW_);
        }

        const int rowoff = (di - 2) * W_;
        #pragma unroll
        for (int g = 0; g < G_; ++g) {
            const float* xr = xb + (size_t)g * WC_ * HW_ + rowoff;
            const float2 z = make_float2(0.f, 0.f);
            float2 xa = (hok && aok) ? *(const float2*)(xr - 2) : z;
            float2 xm =  hok         ? *(const float2*)(xr)     : z;
            float2 xc = (hok && cok) ? *(const float2*)(xr + 2) : z;
            const float xw[6] = {xa.x, xa.y, xm.x, xm.y, xc.x, xc.y};

            #pragma unroll
            for (int dj = 0; dj < 5; ++dj) {
                acc2x[g] += wr2[dj].x * xw[dj];
                acc2y[g] += wr2[dj].y * xw[dj + 1];
            }
            if (di >= 1 && di <= 3) {
                #pragma unroll
                for (int dj = 0; dj < 3; ++dj) {
                    acc1x[g] += wr1[dj].x * xw[dj + 1];
                    acc1y[g] += wr1[dj].y * xw[dj + 2];
                }
            }
        }
    }

    float* o1 = out + ((size_t)(n * 2 + 0) * C_ + v) * HW_ + hw;
    float* o2 = out + ((size_t)(n * 2 + 1) * C_ + v) * HW_ + hw;
    #pragma unroll
    for (int g = 0; g < G_; ++g) {
        *(float2*)(o1 + (size_t)g * WC_ * HW_) = make_float2(acc1x[g], acc1y[g]);
        *(float2*)(o2 + (size_t)g * WC_ * HW_) = make_float2(acc2x[g], acc2y[g]);
    }
}

extern "C" void kernel_launch(void* const* d_in, const int* in_sizes, int n_in,
                              void* d_out, int out_size, void* d_ws, size_t ws_size,
                              hipStream_t stream) {
    const float* x  = (const float*)d_in[0];
    const float* w1 = (const float*)d_in[1];
    const float* w2 = (const float*)d_in[2];
    float* out = (float*)d_out;

    const int total = N_ * WC_ * HW2_;          // 200704 threads
    dim3 grid(total / 256), block(256);
    hipLaunchKernelGGL(lconv_kernel, grid, block, 0, stream, x, w1, w2, out);
}